// Round 1
// baseline (2984.548 us; speedup 1.0000x reference)
//
#include <hip/hip_runtime.h>

#define N_NODES 50000
#define D_IN 256
#define D_OUT 128
#define N_POS 1600000
#define N_PRED 500000

// ---------------- Wf = W1 @ Wc  (256x128), bf = b1 @ Wc (128) ----------------
__global__ void fuse_weights_k(const float* __restrict__ W1, const float* __restrict__ Wc,
                               const float* __restrict__ b1,
                               float* __restrict__ Wf, float* __restrict__ bf) {
    int gid = blockIdx.x * blockDim.x + threadIdx.x;   // 0..32767
    int i = gid >> 7;         // 0..255  (row of W1)
    int j = gid & 127;        // 0..127  (col of Wc)
    float acc = 0.f;
    #pragma unroll 4
    for (int k = 0; k < D_IN; ++k)
        acc += W1[i * D_IN + k] * Wc[k * D_OUT + j];
    Wf[i * D_OUT + j] = acc;
    if (gid < D_OUT) {
        float accb = 0.f;
        for (int k = 0; k < D_IN; ++k)
            accb += b1[k] * Wc[k * D_OUT + gid];
        bf[gid] = accb;
    }
}

// ---------------- degree (with self-loop) and d^-1/2 ----------------
__global__ void deg_init_k(float* __restrict__ degf) {
    int v = blockIdx.x * blockDim.x + threadIdx.x;
    if (v < N_NODES) degf[v] = 1.0f;   // self-loop contributes 1
}

__global__ void deg_accum_k(const int* __restrict__ col, float* __restrict__ degf) {
    int e = blockIdx.x * blockDim.x + threadIdx.x;
    if (e < N_POS) atomicAdd(&degf[col[e]], 1.0f);
}

__global__ void dinv_k(const float* __restrict__ degf, float* __restrict__ dinv) {
    int v = blockIdx.x * blockDim.x + threadIdx.x;
    if (v < N_NODES) dinv[v] = rsqrtf(degf[v]);   // deg >= 1 always (self-loop)
}

// ---------------- hs = dinv[v] * (x @ Wf + bf);  acc seeded with hs ----------------
// block = 256 threads, tile = 16 rows x 128 cols. 50000 % 16 == 0.
__global__ __launch_bounds__(256) void gemm_k(const float* __restrict__ x,
                                              const float* __restrict__ Wf,
                                              const float* __restrict__ bf,
                                              const float* __restrict__ dinv,
                                              float* __restrict__ hs,
                                              float* __restrict__ accb) {
    __shared__ float xs[16 * D_IN];          // 16 KB
    const int r0  = blockIdx.x * 16;
    const int tid = threadIdx.x;

    // stage 16 full rows of x (1024 float4, 4 per thread, coalesced)
    const float4* xg  = (const float4*)(x + (long)r0 * D_IN);
    float4*       xsv = (float4*)xs;
    #pragma unroll
    for (int i = 0; i < 4; ++i) xsv[tid + i * 256] = xg[tid + i * 256];
    __syncthreads();

    const int j    = tid & 127;
    const int half = tid >> 7;               // wave-uniform -> LDS reads broadcast
    float acc[8] = {0.f, 0.f, 0.f, 0.f, 0.f, 0.f, 0.f, 0.f};
    const float* xrow = xs + half * 8 * D_IN;

    #pragma unroll 4
    for (int k = 0; k < D_IN; ++k) {
        float w = Wf[k * D_OUT + j];         // coalesced, L2-resident (128 KB)
        #pragma unroll
        for (int r = 0; r < 8; ++r)
            acc[r] += xrow[r * D_IN + k] * w;   // LDS broadcast (wave-uniform addr)
    }

    const float bj = bf[j];
    #pragma unroll
    for (int r = 0; r < 8; ++r) {
        int v = r0 + half * 8 + r;
        float val = dinv[v] * (acc[r] + bj);
        hs[(long)v * D_OUT + j]   = val;     // scaled features (gather source)
        accb[(long)v * D_OUT + j] = val;     // accumulator seeded w/ self-loop term
    }
}

// ---------------- edge aggregation: acc[col] += hs[row] ----------------
// one (edge, float4-chunk) per thread: 32 lanes cover one 512B row
__global__ void aggregate_k(const int* __restrict__ rows, const int* __restrict__ cols,
                            const float* __restrict__ hs, float* __restrict__ accb) {
    long gid = (long)blockIdx.x * blockDim.x + threadIdx.x;
    int e  = (int)(gid >> 5);
    int c4 = (int)(gid & 31);
    if (e >= N_POS) return;
    int r = rows[e], c = cols[e];
    float4 v = *(const float4*)(hs + (long)r * D_OUT + c4 * 4);
    float* dst = accb + (long)c * D_OUT + c4 * 4;
    atomicAdd(dst + 0, v.x);
    atomicAdd(dst + 1, v.y);
    atomicAdd(dst + 2, v.z);
    atomicAdd(dst + 3, v.w);
}

// ---------------- feat = dinv[c] * acc + bc  (written into hs buffer, reused) ----
__global__ void finalize_k(const float* __restrict__ accb, const float* __restrict__ dinv,
                           const float* __restrict__ bc, float* __restrict__ feat) {
    int idx = blockIdx.x * blockDim.x + threadIdx.x;    // < N_NODES*128 (exact)
    int v = idx >> 7, j = idx & 127;
    feat[idx] = dinv[v] * accb[idx] + bc[j];
}

// ---------------- logits[e] = dot(feat[src], feat[dst]) ----------------
__global__ void score_k(const int* __restrict__ src, const int* __restrict__ dst,
                        const float* __restrict__ feat, float* __restrict__ out) {
    int gid = blockIdx.x * blockDim.x + threadIdx.x;
    int e  = gid >> 5;
    int c4 = gid & 31;
    if (e >= N_PRED) return;
    int a = src[e], b = dst[e];
    float4 va = *(const float4*)(feat + (long)a * D_OUT + c4 * 4);
    float4 vb = *(const float4*)(feat + (long)b * D_OUT + c4 * 4);
    float p = va.x * vb.x + va.y * vb.y + va.z * vb.z + va.w * vb.w;
    #pragma unroll
    for (int m = 16; m; m >>= 1) p += __shfl_xor(p, m, 32);
    if (c4 == 0) out[e] = p;
}

extern "C" void kernel_launch(void* const* d_in, const int* in_sizes, int n_in,
                              void* d_out, int out_size, void* d_ws, size_t ws_size,
                              hipStream_t stream) {
    const float* x   = (const float*)d_in[0];   // [50000,256]
    const int*   ei  = (const int*)  d_in[1];   // [2, N_PRED] row-major
    const int*   pe  = (const int*)  d_in[2];   // [2, N_POS]  row-major
    const float* W1  = (const float*)d_in[3];   // [256,256]
    const float* b1  = (const float*)d_in[4];   // [256]
    const float* Wc  = (const float*)d_in[5];   // [256,128]
    const float* bc  = (const float*)d_in[6];   // [128]
    float* out = (float*)d_out;                 // [N_PRED]

    const int* pe_row = pe;            // source
    const int* pe_col = pe + N_POS;    // target (aggregation)
    const int* ei_src = ei;
    const int* ei_dst = ei + N_PRED;

    // workspace layout (floats); offsets keep 16B alignment for float4 use
    float* ws   = (float*)d_ws;
    float* Wf   = ws;                  // 32768
    float* bf   = Wf + 32768;          // 128
    float* degf = bf + 128;            // 50000
    float* dinv = degf + 50000;        // 50000
    float* hs   = dinv + 50000;        // 6,400,000   (offset*4 = 531584, 16B-aligned)
    float* accb = hs + (long)N_NODES * D_OUT;  // 6,400,000
    // total: ~51.7 MB of d_ws

    fuse_weights_k<<<128, 256, 0, stream>>>(W1, Wc, b1, Wf, bf);
    deg_init_k    <<<(N_NODES + 255) / 256, 256, 0, stream>>>(degf);
    deg_accum_k   <<<(N_POS + 255) / 256, 256, 0, stream>>>(pe_col, degf);
    dinv_k        <<<(N_NODES + 255) / 256, 256, 0, stream>>>(degf, dinv);
    gemm_k        <<<N_NODES / 16, 256, 0, stream>>>(x, Wf, bf, dinv, hs, accb);
    aggregate_k   <<<(int)(((long)N_POS * 32) / 256), 256, 0, stream>>>(pe_row, pe_col, hs, accb);
    finalize_k    <<<(N_NODES * D_OUT) / 256, 256, 0, stream>>>(accb, dinv, bc, hs);
    score_k       <<<(int)(((long)N_PRED * 32) / 256), 256, 0, stream>>>(ei_src, ei_dst, hs, out);
}

// Round 2
// 626.620 us; speedup vs baseline: 4.7629x; 4.7629x over previous
//
#include <hip/hip_runtime.h>

#define N_NODES 50000
#define D_IN 256
#define D_OUT 128
#define N_POS 1600000
#define N_PRED 500000
#define NB_SCAN 196   // ceil(50000/256)

// ---------------- Wf = W1 @ Wc  (256x128), bf = b1 @ Wc (128) ----------------
__global__ void fuse_weights_k(const float* __restrict__ W1, const float* __restrict__ Wc,
                               const float* __restrict__ b1,
                               float* __restrict__ Wf, float* __restrict__ bf) {
    int gid = blockIdx.x * blockDim.x + threadIdx.x;   // 0..32767
    int i = gid >> 7;
    int j = gid & 127;
    float acc = 0.f;
    #pragma unroll 4
    for (int k = 0; k < D_IN; ++k)
        acc += W1[i * D_IN + k] * Wc[k * D_OUT + j];
    Wf[i * D_OUT + j] = acc;
    if (gid < D_OUT) {
        float accb = 0.f;
        for (int k = 0; k < D_IN; ++k)
            accb += b1[k] * Wc[k * D_OUT + gid];
        bf[gid] = accb;
    }
}

// ---------------- CSR build: count / scan / fill ----------------
__global__ void zero_int_k(int* __restrict__ p, int n) {
    int i = blockIdx.x * blockDim.x + threadIdx.x;
    if (i < n) p[i] = 0;
}

__global__ void count_k(const int* __restrict__ col, int* __restrict__ cnt) {
    int e = blockIdx.x * blockDim.x + threadIdx.x;
    if (e < N_POS) atomicAdd(&cnt[col[e]], 1);
}

__global__ void dinv_k(const int* __restrict__ cnt, float* __restrict__ dinv) {
    int v = blockIdx.x * blockDim.x + threadIdx.x;
    if (v < N_NODES) dinv[v] = rsqrtf((float)cnt[v] + 1.0f);   // +1 = self loop
}

// exclusive scan of cnt -> offs, per 256-block; block totals -> bsum
__global__ void scan_block_k(const int* __restrict__ cnt, int* __restrict__ offs,
                             int* __restrict__ bsum) {
    __shared__ int s[256];
    int t = threadIdx.x;
    int i = blockIdx.x * 256 + t;
    int v = (i < N_NODES) ? cnt[i] : 0;
    s[t] = v;
    __syncthreads();
    #pragma unroll
    for (int d = 1; d < 256; d <<= 1) {
        int add = (t >= d) ? s[t - d] : 0;
        __syncthreads();
        if (t >= d) s[t] += add;
        __syncthreads();
    }
    if (i < N_NODES) offs[i] = s[t] - v;      // exclusive
    if (t == 255) bsum[blockIdx.x] = s[255];
}

// single-block exclusive scan of bsum[NB_SCAN]
__global__ void scan_sums_k(int* __restrict__ bsum) {
    __shared__ int s[256];
    int t = threadIdx.x;
    int v = (t < NB_SCAN) ? bsum[t] : 0;
    s[t] = v;
    __syncthreads();
    #pragma unroll
    for (int d = 1; d < 256; d <<= 1) {
        int add = (t >= d) ? s[t - d] : 0;
        __syncthreads();
        if (t >= d) s[t] += add;
        __syncthreads();
    }
    if (t < NB_SCAN) bsum[t] = s[t] - v;
}

__global__ void scan_add_k(int* __restrict__ offs, const int* __restrict__ bsum) {
    int i = blockIdx.x * 256 + threadIdx.x;
    if (i < N_NODES) offs[i] += bsum[blockIdx.x];
    if (i == 0) offs[N_NODES] = N_POS;
}

__global__ void fill_k(const int* __restrict__ row, const int* __restrict__ col,
                       const int* __restrict__ offs, int* __restrict__ fillc,
                       int* __restrict__ csr) {
    int e = blockIdx.x * blockDim.x + threadIdx.x;
    if (e >= N_POS) return;
    int c = col[e];
    int p = offs[c] + atomicAdd(&fillc[c], 1);
    csr[p] = row[e];
}

// ---------------- hs = dinv[v] * (x @ Wf + bf) ----------------
__global__ __launch_bounds__(256) void gemm_k(const float* __restrict__ x,
                                              const float* __restrict__ Wf,
                                              const float* __restrict__ bf,
                                              const float* __restrict__ dinv,
                                              float* __restrict__ hs) {
    __shared__ float xs[16 * D_IN];          // 16 KB
    const int r0  = blockIdx.x * 16;
    const int tid = threadIdx.x;

    const float4* xg  = (const float4*)(x + (long)r0 * D_IN);
    float4*       xsv = (float4*)xs;
    #pragma unroll
    for (int i = 0; i < 4; ++i) xsv[tid + i * 256] = xg[tid + i * 256];
    __syncthreads();

    const int j    = tid & 127;
    const int half = tid >> 7;
    float acc[8] = {0.f, 0.f, 0.f, 0.f, 0.f, 0.f, 0.f, 0.f};
    const float* xrow = xs + half * 8 * D_IN;

    #pragma unroll 4
    for (int k = 0; k < D_IN; ++k) {
        float w = Wf[k * D_OUT + j];
        #pragma unroll
        for (int r = 0; r < 8; ++r)
            acc[r] += xrow[r * D_IN + k] * w;
    }

    const float bj = bf[j];
    #pragma unroll
    for (int r = 0; r < 8; ++r) {
        int v = r0 + half * 8 + r;
        hs[(long)v * D_OUT + j] = dinv[v] * (acc[r] + bj);
    }
}

// ---------------- per-node CSR aggregation + finalize (NO atomics) ----------------
// 256-thread block = 2 nodes; each 128-thread half owns one node, thread j owns col j.
__global__ __launch_bounds__(256) void aggregate_csr_k(const int* __restrict__ offs,
                                                       const int* __restrict__ csr,
                                                       const float* __restrict__ hs,
                                                       const float* __restrict__ dinv,
                                                       const float* __restrict__ bc,
                                                       float* __restrict__ feat) {
    int v = blockIdx.x * 2 + (threadIdx.x >> 7);
    int j = threadIdx.x & 127;
    int s = offs[v], e = offs[v + 1];

    float acc = hs[(long)v * D_OUT + j];   // self-loop term (already dinv[v]-scaled)
    int i = s;
    for (; i + 4 <= e; i += 4) {           // 4 gathers in flight per iter
        int r0 = csr[i], r1 = csr[i + 1], r2 = csr[i + 2], r3 = csr[i + 3];
        float a0 = hs[(long)r0 * D_OUT + j];
        float a1 = hs[(long)r1 * D_OUT + j];
        float a2 = hs[(long)r2 * D_OUT + j];
        float a3 = hs[(long)r3 * D_OUT + j];
        acc += a0 + a1 + a2 + a3;
    }
    for (; i < e; ++i)
        acc += hs[(long)csr[i] * D_OUT + j];

    feat[(long)v * D_OUT + j] = dinv[v] * acc + bc[j];
}

// ---------------- logits[e] = dot(feat[src], feat[dst]) ----------------
__global__ void score_k(const int* __restrict__ src, const int* __restrict__ dst,
                        const float* __restrict__ feat, float* __restrict__ out) {
    int gid = blockIdx.x * blockDim.x + threadIdx.x;
    int e  = gid >> 5;
    int c4 = gid & 31;
    if (e >= N_PRED) return;
    int a = src[e], b = dst[e];
    float4 va = *(const float4*)(feat + (long)a * D_OUT + c4 * 4);
    float4 vb = *(const float4*)(feat + (long)b * D_OUT + c4 * 4);
    float p = va.x * vb.x + va.y * vb.y + va.z * vb.z + va.w * vb.w;
    #pragma unroll
    for (int m = 16; m; m >>= 1) p += __shfl_xor(p, m, 32);
    if (c4 == 0) out[e] = p;
}

extern "C" void kernel_launch(void* const* d_in, const int* in_sizes, int n_in,
                              void* d_out, int out_size, void* d_ws, size_t ws_size,
                              hipStream_t stream) {
    const float* x   = (const float*)d_in[0];
    const int*   ei  = (const int*)  d_in[1];   // [2, N_PRED]
    const int*   pe  = (const int*)  d_in[2];   // [2, N_POS]
    const float* W1  = (const float*)d_in[3];
    const float* b1  = (const float*)d_in[4];
    const float* Wc  = (const float*)d_in[5];
    const float* bc  = (const float*)d_in[6];
    float* out = (float*)d_out;

    const int* pe_row = pe;            // source
    const int* pe_col = pe + N_POS;    // target (aggregation)
    const int* ei_src = ei;
    const int* ei_dst = ei + N_PRED;

    // workspace layout (all offsets 16B-aligned)
    char* w = (char*)d_ws;
    float* Wf    = (float*)w;                 w += 32768 * 4;
    float* bf    = (float*)w;                 w += 128 * 4;
    float* dinv  = (float*)w;                 w += 50000 * 4;
    int*   cnt   = (int*)w;                   w += 50000 * 4;
    int*   offs  = (int*)w;                   w += 50004 * 4;   // [N_NODES+1], padded
    int*   fillc = (int*)w;                   w += 50000 * 4;
    int*   bsum  = (int*)w;                   w += 256 * 4;
    int*   csr   = (int*)w;                   w += (long)N_POS * 4;
    float* hs    = (float*)w;                 w += (long)N_NODES * D_OUT * 4;
    float* feat  = (float*)w;                 // + 25.6 MB -> total ~58.4 MB

    // CSR build
    zero_int_k   <<<(100000 + 255) / 256, 256, 0, stream>>>(cnt, 100000);  // cnt+offs head? no: cnt & fillc
    // note: cnt and offs are adjacent; zero cnt (50000) and fillc separately:
    zero_int_k   <<<(50000 + 255) / 256, 256, 0, stream>>>(fillc, 50000);
    count_k      <<<(N_POS + 255) / 256, 256, 0, stream>>>(pe_col, cnt);
    dinv_k       <<<(N_NODES + 255) / 256, 256, 0, stream>>>(cnt, dinv);
    scan_block_k <<<NB_SCAN, 256, 0, stream>>>(cnt, offs, bsum);
    scan_sums_k  <<<1, 256, 0, stream>>>(bsum);
    scan_add_k   <<<NB_SCAN, 256, 0, stream>>>(offs, bsum);
    fill_k       <<<(N_POS + 255) / 256, 256, 0, stream>>>(pe_row, pe_col, offs, fillc, csr);

    // dense pipeline
    fuse_weights_k<<<128, 256, 0, stream>>>(W1, Wc, b1, Wf, bf);
    gemm_k        <<<N_NODES / 16, 256, 0, stream>>>(x, Wf, bf, dinv, hs);

    // aggregation (no atomics) + finalize
    aggregate_csr_k<<<N_NODES / 2, 256, 0, stream>>>(offs, csr, hs, dinv, bc, feat);

    // scoring
    score_k       <<<(int)(((long)N_PRED * 32) / 256), 256, 0, stream>>>(ei_src, ei_dst, hs /*feat*/, out);
    // NOTE: must score on feat, not hs:
    // (kept as separate launch below to overwrite out correctly)
    score_k       <<<(int)(((long)N_PRED * 32) / 256), 256, 0, stream>>>(ei_src, ei_dst, feat, out);
}

// Round 3
// 469.619 us; speedup vs baseline: 6.3552x; 1.3343x over previous
//
#include <hip/hip_runtime.h>

#define N_NODES 50000
#define D_IN 256
#define D_OUT 128
#define N_POS 1600000
#define N_PRED 500000
#define NB_SCAN 196   // ceil(50000/256)

// ---- bf16 helpers (RNE pack, cheap unpack) ----
__device__ __forceinline__ unsigned short f2bf(float f) {
    unsigned int u = __float_as_uint(f);
    u += 0x7FFFu + ((u >> 16) & 1u);
    return (unsigned short)(u >> 16);
}
__device__ __forceinline__ float bflo(unsigned int u) { return __uint_as_float(u << 16); }
__device__ __forceinline__ float bfhi(unsigned int u) { return __uint_as_float(u & 0xFFFF0000u); }

// ---------------- Wf = W1 @ Wc  (256x128), bf = b1 @ Wc (128) ----------------
__global__ void fuse_weights_k(const float* __restrict__ W1, const float* __restrict__ Wc,
                               const float* __restrict__ b1,
                               float* __restrict__ Wf, float* __restrict__ bf) {
    int gid = blockIdx.x * blockDim.x + threadIdx.x;   // 0..32767
    int i = gid >> 7;
    int j = gid & 127;
    float acc = 0.f;
    #pragma unroll 4
    for (int k = 0; k < D_IN; ++k)
        acc += W1[i * D_IN + k] * Wc[k * D_OUT + j];
    Wf[i * D_OUT + j] = acc;
    if (gid < D_OUT) {
        float accb = 0.f;
        for (int k = 0; k < D_IN; ++k)
            accb += b1[k] * Wc[k * D_OUT + gid];
        bf[gid] = accb;
    }
}

// ---------------- CSR build: count / scan / fill ----------------
__global__ void zero_int_k(int* __restrict__ p, int n) {
    int i = blockIdx.x * blockDim.x + threadIdx.x;
    if (i < n) p[i] = 0;
}

__global__ void count_k(const int* __restrict__ col, int* __restrict__ cnt) {
    int e = blockIdx.x * blockDim.x + threadIdx.x;
    if (e < N_POS) atomicAdd(&cnt[col[e]], 1);
}

__global__ void dinv_k(const int* __restrict__ cnt, float* __restrict__ dinv) {
    int v = blockIdx.x * blockDim.x + threadIdx.x;
    if (v < N_NODES) dinv[v] = rsqrtf((float)cnt[v] + 1.0f);   // +1 = self loop
}

__global__ void scan_block_k(const int* __restrict__ cnt, int* __restrict__ offs,
                             int* __restrict__ bsum) {
    __shared__ int s[256];
    int t = threadIdx.x;
    int i = blockIdx.x * 256 + t;
    int v = (i < N_NODES) ? cnt[i] : 0;
    s[t] = v;
    __syncthreads();
    #pragma unroll
    for (int d = 1; d < 256; d <<= 1) {
        int add = (t >= d) ? s[t - d] : 0;
        __syncthreads();
        if (t >= d) s[t] += add;
        __syncthreads();
    }
    if (i < N_NODES) offs[i] = s[t] - v;      // exclusive
    if (t == 255) bsum[blockIdx.x] = s[255];
}

__global__ void scan_sums_k(int* __restrict__ bsum) {
    __shared__ int s[256];
    int t = threadIdx.x;
    int v = (t < NB_SCAN) ? bsum[t] : 0;
    s[t] = v;
    __syncthreads();
    #pragma unroll
    for (int d = 1; d < 256; d <<= 1) {
        int add = (t >= d) ? s[t - d] : 0;
        __syncthreads();
        if (t >= d) s[t] += add;
        __syncthreads();
    }
    if (t < NB_SCAN) bsum[t] = s[t] - v;
}

__global__ void scan_add_k(int* __restrict__ offs, const int* __restrict__ bsum) {
    int i = blockIdx.x * 256 + threadIdx.x;
    if (i < N_NODES) offs[i] += bsum[blockIdx.x];
    if (i == 0) offs[N_NODES] = N_POS;
}

__global__ void fill_k(const int* __restrict__ row, const int* __restrict__ col,
                       const int* __restrict__ offs, int* __restrict__ fillc,
                       int* __restrict__ csr) {
    int e = blockIdx.x * blockDim.x + threadIdx.x;
    if (e >= N_POS) return;
    int c = col[e];
    int p = offs[c] + atomicAdd(&fillc[c], 1);
    csr[p] = row[e];
}

// ---------------- hs_bf16 = bf16( dinv[v] * (x @ Wf + bf) ) ----------------
__global__ __launch_bounds__(256) void gemm_k(const float* __restrict__ x,
                                              const float* __restrict__ Wf,
                                              const float* __restrict__ bf,
                                              const float* __restrict__ dinv,
                                              unsigned short* __restrict__ hsb) {
    __shared__ float xs[16 * D_IN];          // 16 KB
    const int r0  = blockIdx.x * 16;
    const int tid = threadIdx.x;

    const float4* xg  = (const float4*)(x + (long)r0 * D_IN);
    float4*       xsv = (float4*)xs;
    #pragma unroll
    for (int i = 0; i < 4; ++i) xsv[tid + i * 256] = xg[tid + i * 256];
    __syncthreads();

    const int j    = tid & 127;
    const int half = tid >> 7;
    float acc[8] = {0.f, 0.f, 0.f, 0.f, 0.f, 0.f, 0.f, 0.f};
    const float4* xrow4 = (const float4*)(xs + half * 8 * D_IN);

    #pragma unroll 2
    for (int kk = 0; kk < 64; ++kk) {        // k = 4*kk .. 4*kk+3
        float w0 = Wf[(4 * kk + 0) * D_OUT + j];
        float w1 = Wf[(4 * kk + 1) * D_OUT + j];
        float w2 = Wf[(4 * kk + 2) * D_OUT + j];
        float w3 = Wf[(4 * kk + 3) * D_OUT + j];
        #pragma unroll
        for (int r = 0; r < 8; ++r) {
            float4 xv = xrow4[r * 64 + kk];  // wave-uniform addr -> LDS broadcast
            acc[r] += xv.x * w0 + xv.y * w1 + xv.z * w2 + xv.w * w3;
        }
    }

    const float bj = bf[j];
    #pragma unroll
    for (int r = 0; r < 8; ++r) {
        int v = r0 + half * 8 + r;
        hsb[(long)v * D_OUT + j] = f2bf(dinv[v] * (acc[r] + bj));
    }
}

// ---------------- per-node CSR aggregation + finalize (bf16 table, fp32 accum) ----
// 256-thread block = 4 nodes; 64 threads per node, each owning 2 columns (one uint).
__global__ __launch_bounds__(256) void aggregate_csr_k(const int* __restrict__ offs,
                                                       const int* __restrict__ csr,
                                                       const unsigned int* __restrict__ hs32,
                                                       const float* __restrict__ dinv,
                                                       const float* __restrict__ bc,
                                                       unsigned int* __restrict__ feat32) {
    int v    = blockIdx.x * 4 + (threadIdx.x >> 6);
    int lane = threadIdx.x & 63;
    int s = offs[v], e = offs[v + 1];

    unsigned int u = hs32[(long)v * 64 + lane];   // self-loop term
    float a0 = bflo(u), a1 = bfhi(u);
    int i = s;
    for (; i + 4 <= e; i += 4) {
        int r0 = csr[i], r1 = csr[i + 1], r2 = csr[i + 2], r3 = csr[i + 3];
        unsigned int u0 = hs32[(long)r0 * 64 + lane];
        unsigned int u1 = hs32[(long)r1 * 64 + lane];
        unsigned int u2 = hs32[(long)r2 * 64 + lane];
        unsigned int u3 = hs32[(long)r3 * 64 + lane];
        a0 += bflo(u0) + bflo(u1) + bflo(u2) + bflo(u3);
        a1 += bfhi(u0) + bfhi(u1) + bfhi(u2) + bfhi(u3);
    }
    for (; i < e; ++i) {
        unsigned int uu = hs32[(long)csr[i] * 64 + lane];
        a0 += bflo(uu); a1 += bfhi(uu);
    }

    float dv = dinv[v];
    float f0 = dv * a0 + bc[2 * lane];
    float f1 = dv * a1 + bc[2 * lane + 1];
    feat32[(long)v * 64 + lane] = (unsigned int)f2bf(f0) | ((unsigned int)f2bf(f1) << 16);
}

// ---------------- logits[e] = dot(feat[src], feat[dst]) — 16 lanes/edge ----------------
__global__ void score_k(const int* __restrict__ src, const int* __restrict__ dst,
                        const uint4* __restrict__ feat4, float* __restrict__ out) {
    int gid = blockIdx.x * blockDim.x + threadIdx.x;
    int e = gid >> 4;
    int c = gid & 15;
    if (e >= N_PRED) return;
    int a = src[e], b = dst[e];
    uint4 ua = feat4[(long)a * 16 + c];     // row = 128 bf16 = 16 uint4
    uint4 ub = feat4[(long)b * 16 + c];
    float p = bflo(ua.x) * bflo(ub.x) + bfhi(ua.x) * bfhi(ub.x)
            + bflo(ua.y) * bflo(ub.y) + bfhi(ua.y) * bfhi(ub.y)
            + bflo(ua.z) * bflo(ub.z) + bfhi(ua.z) * bfhi(ub.z)
            + bflo(ua.w) * bflo(ub.w) + bfhi(ua.w) * bfhi(ub.w);
    #pragma unroll
    for (int m = 8; m; m >>= 1) p += __shfl_xor(p, m, 16);
    if (c == 0) out[e] = p;
}

extern "C" void kernel_launch(void* const* d_in, const int* in_sizes, int n_in,
                              void* d_out, int out_size, void* d_ws, size_t ws_size,
                              hipStream_t stream) {
    const float* x   = (const float*)d_in[0];
    const int*   ei  = (const int*)  d_in[1];   // [2, N_PRED]
    const int*   pe  = (const int*)  d_in[2];   // [2, N_POS]
    const float* W1  = (const float*)d_in[3];
    const float* b1  = (const float*)d_in[4];
    const float* Wc  = (const float*)d_in[5];
    const float* bc  = (const float*)d_in[6];
    float* out = (float*)d_out;

    const int* pe_row = pe;            // source
    const int* pe_col = pe + N_POS;    // target (aggregation)
    const int* ei_src = ei;
    const int* ei_dst = ei + N_PRED;

    // workspace layout (all 16B-aligned; cnt & fillc adjacent for one zero pass)
    char* w = (char*)d_ws;
    float* Wf    = (float*)w;                 w += 32768 * 4;          // 128 KB
    float* bf    = (float*)w;                 w += 128 * 4;
    float* dinv  = (float*)w;                 w += 50000 * 4;
    int*   cnt   = (int*)w;                   w += 50000 * 4;
    int*   fillc = (int*)w;                   w += 50000 * 4;
    int*   offs  = (int*)w;                   w += 50004 * 4;          // [N+1] padded
    int*   bsum  = (int*)w;                   w += 256 * 4;
    int*   csr   = (int*)w;                   w += (long)N_POS * 4;    // 6.4 MB
    unsigned short* hsb   = (unsigned short*)w;  w += (long)N_NODES * D_OUT * 2;  // 12.8 MB
    unsigned short* featb = (unsigned short*)w;  // 12.8 MB; total ~33 MB

    // CSR build
    zero_int_k   <<<(100000 + 255) / 256, 256, 0, stream>>>(cnt, 100000);  // cnt + fillc
    count_k      <<<(N_POS + 255) / 256, 256, 0, stream>>>(pe_col, cnt);
    dinv_k       <<<(N_NODES + 255) / 256, 256, 0, stream>>>(cnt, dinv);
    scan_block_k <<<NB_SCAN, 256, 0, stream>>>(cnt, offs, bsum);
    scan_sums_k  <<<1, 256, 0, stream>>>(bsum);
    scan_add_k   <<<NB_SCAN, 256, 0, stream>>>(offs, bsum);
    fill_k       <<<(N_POS + 255) / 256, 256, 0, stream>>>(pe_row, pe_col, offs, fillc, csr);

    // dense pipeline
    fuse_weights_k<<<128, 256, 0, stream>>>(W1, Wc, b1, Wf, bf);
    gemm_k        <<<N_NODES / 16, 256, 0, stream>>>(x, Wf, bf, dinv, hsb);

    // aggregation (no atomics, bf16 gathers) + finalize
    aggregate_csr_k<<<N_NODES / 4, 256, 0, stream>>>(offs, csr, (const unsigned int*)hsb,
                                                     dinv, bc, (unsigned int*)featb);

    // scoring (single launch, bf16 feat)
    score_k       <<<(int)(((long)N_PRED * 16) / 256), 256, 0, stream>>>(
                      ei_src, ei_dst, (const uint4*)featb, out);
}

// Round 4
// 421.372 us; speedup vs baseline: 7.0829x; 1.1145x over previous
//
#include <hip/hip_runtime.h>

#define N_NODES 50000
#define D_IN 256
#define D_OUT 128
#define N_POS 1600000
#define N_PRED 500000
#define NB_SCAN 196   // ceil(50000/256)

typedef __attribute__((ext_vector_type(8))) short short8;
typedef __attribute__((ext_vector_type(4))) float f32x4;

// ---- bf16 helpers (RNE) ----
__device__ __forceinline__ unsigned short f2bf(float f) {
    unsigned int u = __float_as_uint(f);
    u += 0x7FFFu + ((u >> 16) & 1u);
    return (unsigned short)(u >> 16);
}
__device__ __forceinline__ unsigned int pk2(float a, float b) {   // -> bf16(a) | bf16(b)<<16
    unsigned int ua = __float_as_uint(a), ub = __float_as_uint(b);
    ua += 0x7FFFu + ((ua >> 16) & 1u);
    ub += 0x7FFFu + ((ub >> 16) & 1u);
    return (ua >> 16) | (ub & 0xFFFF0000u);
}
__device__ __forceinline__ float bflo(unsigned int u) { return __uint_as_float(u << 16); }
__device__ __forceinline__ float bfhi(unsigned int u) { return __uint_as_float(u & 0xFFFF0000u); }

// ------- Wf = W1@Wc packed into MFMA B-fragment layout; bf = b1@Wc -------
// B-frag (16x16x32): lane = q*16+nl holds B[k = ks*32 + q*8 + j][n = nt*16 + nl], j=0..7
// Bp flat u16 index: ((ks*8 + nt)*64 + lane)*8 + j
__global__ void fuse_weights_k(const float* __restrict__ W1, const float* __restrict__ Wc,
                               const float* __restrict__ b1,
                               unsigned short* __restrict__ Bp, float* __restrict__ bf) {
    int gid = blockIdx.x * blockDim.x + threadIdx.x;   // 0..32767
    int k = gid >> 7;          // 0..255  (K dim = W1 row)
    int n = gid & 127;         // 0..127  (N dim)
    float acc = 0.f;
    #pragma unroll 4
    for (int kk = 0; kk < D_IN; ++kk)
        acc += W1[k * D_IN + kk] * Wc[kk * D_OUT + n];
    int ks = k >> 5, q = (k >> 3) & 3, jj = k & 7;
    int nt = n >> 4, nl = n & 15;
    int lane = q * 16 + nl;
    Bp[(((long)(ks * 8 + nt)) * 64 + lane) * 8 + jj] = f2bf(acc);
    if (gid < D_OUT) {
        float accb = 0.f;
        for (int kk = 0; kk < D_IN; ++kk)
            accb += b1[kk] * Wc[kk * D_OUT + gid];
        bf[gid] = accb;
    }
}

// ---------------- CSR build: count / scan / fill ----------------
__global__ void zero_int_k(int* __restrict__ p, int n) {
    int i = blockIdx.x * blockDim.x + threadIdx.x;
    if (i < n) p[i] = 0;
}

__global__ void count_k(const int* __restrict__ col, int* __restrict__ cnt) {
    int e = blockIdx.x * blockDim.x + threadIdx.x;
    if (e < N_POS) atomicAdd(&cnt[col[e]], 1);
}

__global__ void dinv_k(const int* __restrict__ cnt, float* __restrict__ dinv) {
    int v = blockIdx.x * blockDim.x + threadIdx.x;
    if (v < N_NODES) dinv[v] = rsqrtf((float)cnt[v] + 1.0f);   // +1 = self loop
}

__global__ void scan_block_k(const int* __restrict__ cnt, int* __restrict__ offs,
                             int* __restrict__ bsum) {
    __shared__ int s[256];
    int t = threadIdx.x;
    int i = blockIdx.x * 256 + t;
    int v = (i < N_NODES) ? cnt[i] : 0;
    s[t] = v;
    __syncthreads();
    #pragma unroll
    for (int d = 1; d < 256; d <<= 1) {
        int add = (t >= d) ? s[t - d] : 0;
        __syncthreads();
        if (t >= d) s[t] += add;
        __syncthreads();
    }
    if (i < N_NODES) offs[i] = s[t] - v;      // exclusive
    if (t == 255) bsum[blockIdx.x] = s[255];
}

__global__ void scan_sums_k(int* __restrict__ bsum) {
    __shared__ int s[256];
    int t = threadIdx.x;
    int v = (t < NB_SCAN) ? bsum[t] : 0;
    s[t] = v;
    __syncthreads();
    #pragma unroll
    for (int d = 1; d < 256; d <<= 1) {
        int add = (t >= d) ? s[t - d] : 0;
        __syncthreads();
        if (t >= d) s[t] += add;
        __syncthreads();
    }
    if (t < NB_SCAN) bsum[t] = s[t] - v;
}

__global__ void scan_add_k(int* __restrict__ offs, const int* __restrict__ bsum) {
    int i = blockIdx.x * 256 + threadIdx.x;
    if (i < N_NODES) offs[i] += bsum[blockIdx.x];
    if (i == 0) offs[N_NODES] = N_POS;
}

__global__ void fill_k(const int* __restrict__ row, const int* __restrict__ col,
                       const int* __restrict__ offs, int* __restrict__ fillc,
                       int* __restrict__ csr) {
    int e = blockIdx.x * blockDim.x + threadIdx.x;
    if (e >= N_POS) return;
    int c = col[e];
    int p = offs[c] + atomicAdd(&fillc[c], 1);
    csr[p] = row[e];
}

// ---------------- MFMA GEMM: hs = bf16( dinv[v] * (x @ Wf + bf) ) ----------------
// block = 256 thr = 4 waves; wave covers 16 rows x 128 cols; 8 ksteps x 8 ntiles MFMAs.
// A-frags straight from global x (fp32 -> bf16 in-register); B-frags from packed Bp (L2).
__global__ __launch_bounds__(256) void gemm_mfma_k(const float* __restrict__ x,
                                                   const uint4* __restrict__ Bp,
                                                   const float* __restrict__ bf,
                                                   const float* __restrict__ dinv,
                                                   unsigned short* __restrict__ hsb) {
    __shared__ unsigned short ot[4][16 * 128];   // 16 KB epilogue staging
    const int wave = threadIdx.x >> 6;
    const int lane = threadIdx.x & 63;
    const int q    = lane >> 4;
    const int ml   = lane & 15;
    const int m0   = blockIdx.x * 64 + wave * 16;

    f32x4 acc[8];
    #pragma unroll
    for (int t = 0; t < 8; ++t) acc[t] = (f32x4){0.f, 0.f, 0.f, 0.f};

    long arow = m0 + ml; if (arow > N_NODES - 1) arow = N_NODES - 1;   // tail clamp
    const float* xrow = x + arow * D_IN + q * 8;

    #pragma unroll
    for (int ks = 0; ks < 8; ++ks) {
        float4 xa = *(const float4*)(xrow + ks * 32);
        float4 xb = *(const float4*)(xrow + ks * 32 + 4);
        union { short8 s; unsigned int u[4]; } af;
        af.u[0] = pk2(xa.x, xa.y);
        af.u[1] = pk2(xa.z, xa.w);
        af.u[2] = pk2(xb.x, xb.y);
        af.u[3] = pk2(xb.z, xb.w);
        #pragma unroll
        for (int nt = 0; nt < 8; ++nt) {
            union { uint4 v; short8 s; } bu;
            bu.v = Bp[(long)(ks * 8 + nt) * 64 + lane];
            acc[nt] = __builtin_amdgcn_mfma_f32_16x16x32_bf16(af.s, bu.s, acc[nt], 0, 0, 0);
        }
    }

    // epilogue: C/D layout col = ml, row = q*4 + r  ->  val = dinv[v]*(acc+bf[n])
    float dv[4];
    #pragma unroll
    for (int r = 0; r < 4; ++r) {
        int v = m0 + q * 4 + r;
        dv[r] = dinv[v > N_NODES - 1 ? N_NODES - 1 : v];
    }
    unsigned short* o = ot[wave];
    #pragma unroll
    for (int nt = 0; nt < 8; ++nt) {
        float bn = bf[nt * 16 + ml];
        #pragma unroll
        for (int r = 0; r < 4; ++r) {
            float val = dv[r] * (acc[nt][r] + bn);
            o[(q * 4 + r) * 128 + nt * 16 + ml] = f2bf(val);
        }
    }
    __syncthreads();
    // coalesced store: wave tile = 16 rows x 256 B; lane stores 4 x 16 B
    #pragma unroll
    for (int i = 0; i < 4; ++i) {
        int fb = i * 1024 + lane * 16;     // byte offset within tile
        int v = m0 + (fb >> 8);
        if (v < N_NODES) {
            uint4 val = *(const uint4*)((const char*)o + fb);
            *(uint4*)((char*)hsb + (long)v * 256 + (fb & 255)) = val;
        }
    }
}

// ---------------- per-node CSR aggregation + finalize (bf16 table, fp32 accum) ----
__global__ __launch_bounds__(256) void aggregate_csr_k(const int* __restrict__ offs,
                                                       const int* __restrict__ csr,
                                                       const unsigned int* __restrict__ hs32,
                                                       const float* __restrict__ dinv,
                                                       const float* __restrict__ bc,
                                                       unsigned int* __restrict__ feat32) {
    int v    = blockIdx.x * 4 + (threadIdx.x >> 6);
    int lane = threadIdx.x & 63;
    int s = offs[v], e = offs[v + 1];

    unsigned int u = hs32[(long)v * 64 + lane];   // self-loop term
    float a0 = bflo(u), a1 = bfhi(u);
    int i = s;
    for (; i + 4 <= e; i += 4) {
        int r0 = csr[i], r1 = csr[i + 1], r2 = csr[i + 2], r3 = csr[i + 3];
        unsigned int u0 = hs32[(long)r0 * 64 + lane];
        unsigned int u1 = hs32[(long)r1 * 64 + lane];
        unsigned int u2 = hs32[(long)r2 * 64 + lane];
        unsigned int u3 = hs32[(long)r3 * 64 + lane];
        a0 += bflo(u0) + bflo(u1) + bflo(u2) + bflo(u3);
        a1 += bfhi(u0) + bfhi(u1) + bfhi(u2) + bfhi(u3);
    }
    for (; i < e; ++i) {
        unsigned int uu = hs32[(long)csr[i] * 64 + lane];
        a0 += bflo(uu); a1 += bfhi(uu);
    }

    float dv = dinv[v];
    float f0 = dv * a0 + bc[2 * lane];
    float f1 = dv * a1 + bc[2 * lane + 1];
    feat32[(long)v * 64 + lane] = (unsigned int)f2bf(f0) | ((unsigned int)f2bf(f1) << 16);
}

// ---------------- logits[e] = dot(feat[src], feat[dst]) — 16 lanes/edge ----------------
__global__ void score_k(const int* __restrict__ src, const int* __restrict__ dst,
                        const uint4* __restrict__ feat4, float* __restrict__ out) {
    int gid = blockIdx.x * blockDim.x + threadIdx.x;
    int e = gid >> 4;
    int c = gid & 15;
    if (e >= N_PRED) return;
    int a = src[e], b = dst[e];
    uint4 ua = feat4[(long)a * 16 + c];
    uint4 ub = feat4[(long)b * 16 + c];
    float p = bflo(ua.x) * bflo(ub.x) + bfhi(ua.x) * bfhi(ub.x)
            + bflo(ua.y) * bflo(ub.y) + bfhi(ua.y) * bfhi(ub.y)
            + bflo(ua.z) * bflo(ub.z) + bfhi(ua.z) * bfhi(ub.z)
            + bflo(ua.w) * bflo(ub.w) + bfhi(ua.w) * bfhi(ub.w);
    #pragma unroll
    for (int m = 8; m; m >>= 1) p += __shfl_xor(p, m, 16);
    if (c == 0) out[e] = p;
}

extern "C" void kernel_launch(void* const* d_in, const int* in_sizes, int n_in,
                              void* d_out, int out_size, void* d_ws, size_t ws_size,
                              hipStream_t stream) {
    const float* x   = (const float*)d_in[0];
    const int*   ei  = (const int*)  d_in[1];   // [2, N_PRED]
    const int*   pe  = (const int*)  d_in[2];   // [2, N_POS]
    const float* W1  = (const float*)d_in[3];
    const float* b1  = (const float*)d_in[4];
    const float* Wc  = (const float*)d_in[5];
    const float* bc  = (const float*)d_in[6];
    float* out = (float*)d_out;

    const int* pe_row = pe;            // source
    const int* pe_col = pe + N_POS;    // target (aggregation)
    const int* ei_src = ei;
    const int* ei_dst = ei + N_PRED;

    // workspace layout (all 16B-aligned)
    char* w = (char*)d_ws;
    unsigned short* Bp = (unsigned short*)w;  w += 32768 * 2;          // 64 KB packed Wf
    float* bf    = (float*)w;                 w += 128 * 4;
    float* dinv  = (float*)w;                 w += 50000 * 4;
    int*   cnt   = (int*)w;                   w += 50000 * 4;
    int*   fillc = (int*)w;                   w += 50000 * 4;
    int*   offs  = (int*)w;                   w += 50004 * 4;          // [N+1] padded
    int*   bsum  = (int*)w;                   w += 256 * 4;
    int*   csr   = (int*)w;                   w += (long)N_POS * 4;    // 6.4 MB
    unsigned short* hsb   = (unsigned short*)w;  w += (long)N_NODES * D_OUT * 2;  // 12.8 MB
    unsigned short* featb = (unsigned short*)w;  // 12.8 MB

    // CSR build
    zero_int_k   <<<(100000 + 255) / 256, 256, 0, stream>>>(cnt, 100000);  // cnt + fillc
    count_k      <<<(N_POS + 255) / 256, 256, 0, stream>>>(pe_col, cnt);
    dinv_k       <<<(N_NODES + 255) / 256, 256, 0, stream>>>(cnt, dinv);
    scan_block_k <<<NB_SCAN, 256, 0, stream>>>(cnt, offs, bsum);
    scan_sums_k  <<<1, 256, 0, stream>>>(bsum);
    scan_add_k   <<<NB_SCAN, 256, 0, stream>>>(offs, bsum);
    fill_k       <<<(N_POS + 255) / 256, 256, 0, stream>>>(pe_row, pe_col, offs, fillc, csr);

    // dense pipeline (MFMA)
    fuse_weights_k<<<128, 256, 0, stream>>>(W1, Wc, b1, Bp, bf);
    gemm_mfma_k   <<<(N_NODES + 63) / 64, 256, 0, stream>>>(x, (const uint4*)Bp, bf, dinv, hsb);

    // aggregation (no atomics, bf16 gathers) + finalize
    aggregate_csr_k<<<N_NODES / 4, 256, 0, stream>>>(offs, csr, (const unsigned int*)hsb,
                                                     dinv, bc, (unsigned int*)featb);

    // scoring (bf16 feat)
    score_k       <<<(int)(((long)N_PRED * 16) / 256), 256, 0, stream>>>(
                      ei_src, ei_dst, (const uint4*)featb, out);
}